// Round 20
// baseline (1025.338 us; speedup 1.0000x reference)
//
#include <hip/hip_runtime.h>
#include <hip/hip_bf16.h>

#define NB 16
#define SEQ 2048
#define EDIM 256

typedef __attribute__((ext_vector_type(16))) float f32x16;
typedef __attribute__((ext_vector_type(4)))  float f32x4;
typedef __attribute__((ext_vector_type(8)))  short short8;

static __device__ __forceinline__ ushort f2bf(float f) {
    uint32_t u = __float_as_uint(f);
    uint32_t r = (u + 0x7fffu + ((u >> 16) & 1u)) >> 16;
    return (ushort)r;
}
static __device__ __forceinline__ float bf2f(ushort h) {
    return __uint_as_float(((uint32_t)h) << 16);
}
// async global->LDS, 16 bytes per lane; LDS dest wave-uniform, global src per-lane.
static __device__ __forceinline__ void gll16(const ushort* g, ushort* l) {
    __builtin_amdgcn_global_load_lds(
        (const __attribute__((address_space(1))) uint32_t*)g,
        (__attribute__((address_space(3))) uint32_t*)l,
        16, 0, 0);
}
// raw barrier: lgkm-only wait, never drains in-flight vmem stores
static __device__ __forceinline__ void lgkm_barrier() {
    asm volatile("s_waitcnt lgkmcnt(0)" ::: "memory");
    __builtin_amdgcn_sched_barrier(0);
    __builtin_amdgcn_s_barrier();
    asm volatile("" ::: "memory");
}

// Kernel 1: fp32 -> bf16 in K-MAJOR PANEL layout xb[b][ks][t][j] (ks=e>>4,
// j=e&15), plus per-row sum of squares of the bf16-rounded values (distance
// diagonal cancels exactly against the fp32-accumulated MFMA gram).
__global__ void prep_kernel(const float* __restrict__ x,
                            ushort* __restrict__ xb,
                            float* __restrict__ sq) {
    __shared__ ushort sh[4][256];
    const int tid  = threadIdx.x;
    const int r    = tid >> 6;
    const int lane = tid & 63;
    const int grow = blockIdx.x * 4;
    const int row  = grow + r;

    const f32x4* xp = reinterpret_cast<const f32x4*>(x + (size_t)row * EDIM + lane * 4);
    const f32x4 v = __builtin_nontemporal_load(xp);
    ushort h0 = f2bf(v.x), h1 = f2bf(v.y), h2 = f2bf(v.z), h3 = f2bf(v.w);
    ushort4 h; h.x = h0; h.y = h1; h.z = h2; h.w = h3;
    *reinterpret_cast<ushort4*>(&sh[r][lane * 4]) = h;

    const float fx = bf2f(h0), fy = bf2f(h1), fz = bf2f(h2), fw = bf2f(h3);
    float s = fx * fx + fy * fy + fz * fz + fw * fw;
    #pragma unroll
    for (int m = 1; m < 64; m <<= 1) s += __shfl_xor(s, m);
    if (lane == 0) sq[row] = s;

    __syncthreads();

    const int b   = grow >> 11;
    const int t0  = grow & 2047;
    const int ksx = tid >> 4;
    const int idx = tid & 15;
    const int r2  = idx >> 2;
    const int j   = (idx & 3) * 4;
    ushort4 o = *reinterpret_cast<ushort4*>(&sh[r2][ksx * 16 + j]);
    *reinterpret_cast<ushort4*>(xb + (size_t)b * SEQ * EDIM
                                   + (size_t)ksx * SEQ * 16
                                   + (size_t)(t0 + r2) * 16 + j) = o;
}

// Kernel 2: fused gram-GEMM + one-pass softmax. R12 structure with 64-ROW
// blocks: each B fragment feeds TWO 32-row MFMA sets (acc_lo/acc_hi) ->
// B L2-read traffic halves (4->2 MB/CU) and compute-per-load doubles.
// 2 blocks/WG, grid (16,16) = 1 WG/CU; acc 128 VGPRs -> launch_bounds
// (1024,2). Laws kept: no stores in K-loop (R8/R13/R16), plain stores
// (R12), counted vmcnt(32) at block top (A prefetched BEFORE the burst),
// separate 8-row-chunk transpose-burst store phases.
__global__ __launch_bounds__(1024, 2) void sims_main(
        const ushort* __restrict__ xb,
        const float*  __restrict__ sq,
        float* __restrict__ out) {
    __shared__ __align__(16) ushort Ab[2][16 * 1024];  // 2 x 32 KB A panels (64 rows)
    __shared__ __align__(16) float Tr[8][2048];        // 64 KB transpose buffer
    __shared__ float red[64][17];
    __shared__ float inv_s[64];

    const int b    = blockIdx.x;        // batch -> XCD = flat%8 = b%8
    const int g    = blockIdx.y;        // rows [g*128,(g+1)*128), 2 blocks of 64
    const int tid  = threadIdx.x;
    const int wave = tid >> 6;          // 0..15
    const int lane = tid & 63;
    const int l31  = lane & 31;
    const int hi   = lane >> 5;

    const ushort* xbB = xb + (size_t)b * SEQ * EDIM;
    const float*  sqB = sq + b * SEQ;
    float* outB = out + (size_t)b * SEQ * SEQ;

    const int colw = wave * 128;
    const ushort* bbase = xbB + ((size_t)colw + l31) * 16 + hi * 8;
    const int gl  = lane ^ ((lane >> 3) & 7);       // A-stage src swizzle (involution)
    const int r6  = l31 * 2 + hi;
    const int pr6 = r6 ^ ((r6 >> 3) & 7);           // swizzled A read chunk (lower 32)
    // upper 32 rows: chunk 64+r6, perm(64+c) = 64+perm(c)

    constexpr float kC   = (float)(-1.4426950408889634 / 13.544);  // -log2(e)/T
    constexpr float m2kC = -2.0f * kC;
    float kcc[4];
    #pragma unroll
    for (int cb = 0; cb < 4; ++cb) kcc[cb] = kC * sqB[colw + cb * 32 + l31];

    // A stage: wave w covers ks=w, two 64-chunk halves (i=0,1).
    // position pos = i*64+lane holds chunk i*64+gl of ks=w.
    #define STAGE_A(buf, rbase)                                                   \
        {                                                                         \
            _Pragma("unroll")                                                     \
            for (int i_ = 0; i_ < 2; ++i_) {                                      \
                const int c_ = i_ * 64 + gl;                                      \
                gll16(xbB + (size_t)wave * (SEQ * 16)                             \
                          + (size_t)((rbase) + (c_ >> 1)) * 16 + (c_ & 1) * 8,    \
                      &Ab[(buf)][wave * 1024 + i_ * 512]);                        \
            }                                                                     \
        }

    // prologue: stage A panel for block 0 (64 rows)
    STAGE_A(0, g * 128);

    const int row8 = wave >> 1;          // burst: row within 8-row chunk
    const int half = wave & 1;           // which 4KB half of the row

    #pragma unroll 1
    for (int rb = 0; rb < 2; ++rb) {
        // A-panel ready; prev block's <=32 stores may stay in flight.
        if (rb == 0) { asm volatile("s_waitcnt vmcnt(0)" ::: "memory"); }
        else         { asm volatile("s_waitcnt vmcnt(32)" ::: "memory"); }
        __builtin_amdgcn_sched_barrier(0);
        __builtin_amdgcn_s_barrier();
        __builtin_amdgcn_sched_barrier(0);

        const int row_base = g * 128 + rb * 64;
        const ushort* AbC = &Ab[rb][0];

        f32x16 accL[4], accH[4];
        #pragma unroll
        for (int cb = 0; cb < 4; ++cb) { accL[cb] = (f32x16)0.0f; accH[cb] = (f32x16)0.0f; }

        #pragma unroll 2
        for (int ks = 0; ks < 16; ++ks) {
            const ushort* bks = bbase + (size_t)ks * (SEQ * 16);
            short8 bv[4];
            #pragma unroll
            for (int cb = 0; cb < 4; ++cb)
                bv[cb] = *reinterpret_cast<const short8*>(bks + cb * 512);
            const short8 a0 = *reinterpret_cast<const short8*>(AbC + ks * 1024 + pr6 * 8);
            const short8 a1 = *reinterpret_cast<const short8*>(AbC + ks * 1024 + 512 + pr6 * 8);
            #pragma unroll
            for (int cb = 0; cb < 4; ++cb)
                accL[cb] = __builtin_amdgcn_mfma_f32_32x32x16_bf16(a0, bv[cb], accL[cb], 0, 0, 0);
            #pragma unroll
            for (int cb = 0; cb < 4; ++cb)
                accH[cb] = __builtin_amdgcn_mfma_f32_32x32x16_bf16(a1, bv[cb], accH[cb], 0, 0, 0);
        }

        // prefetch next block's A panel (before any stores are issued)
        if (rb == 0) STAGE_A(1, g * 128 + 64);

        // ---- epilogue: exp(-dist/T), row sums for 64 rows ----
        float part[16];
        #pragma unroll
        for (int r = 0; r < 16; ++r) {
            const int lr = (r & 3) + 8 * (r >> 2) + 4 * hi;
            const float kcr = kC * sqB[row_base + lr];
            float p = 0.0f;
            #pragma unroll
            for (int cb = 0; cb < 4; ++cb) {
                const float e = exp2f(fmaf(m2kC, accL[cb][r], kcr + kcc[cb]));
                accL[cb][r] = e;
                p += e;
            }
            part[r] = p;
        }
        #pragma unroll
        for (int r = 0; r < 16; ++r) {
            float p = part[r];
            p += __shfl_xor(p, 1);
            p += __shfl_xor(p, 2);
            p += __shfl_xor(p, 4);
            p += __shfl_xor(p, 8);
            p += __shfl_xor(p, 16);
            if (l31 == 0) red[(r & 3) + 8 * (r >> 2) + 4 * hi][wave] = p;
        }
        #pragma unroll
        for (int r = 0; r < 16; ++r) {
            const int lr = (r & 3) + 8 * (r >> 2) + 4 * hi;
            const float kcr = kC * sqB[row_base + 32 + lr];
            float p = 0.0f;
            #pragma unroll
            for (int cb = 0; cb < 4; ++cb) {
                const float e = exp2f(fmaf(m2kC, accH[cb][r], kcr + kcc[cb]));
                accH[cb][r] = e;
                p += e;
            }
            part[r] = p;
        }
        #pragma unroll
        for (int r = 0; r < 16; ++r) {
            float p = part[r];
            p += __shfl_xor(p, 1);
            p += __shfl_xor(p, 2);
            p += __shfl_xor(p, 4);
            p += __shfl_xor(p, 8);
            p += __shfl_xor(p, 16);
            if (l31 == 0) red[32 + (r & 3) + 8 * (r >> 2) + 4 * hi][wave] = p;
        }
        lgkm_barrier();
        if (tid < 64) {
            float s = 0.0f;
            #pragma unroll
            for (int w = 0; w < 16; ++w) s += red[tid][w];
            inv_s[tid] = 1.0f / s;
        }
        lgkm_barrier();

        // ---- transpose-burst store: 8 chunks x 8 rows through LDS ----
        #pragma unroll 1
        for (int c = 0; c < 4; ++c) {          // chunks 0..3: accL
            #pragma unroll
            for (int rr = 0; rr < 4; ++rr) {
                const int r    = 4 * c + rr;
                const int lrow = rr + 8 * c + 4 * hi;
                const int lr8  = rr + 4 * hi;
                const float scale = inv_s[lrow];
                #pragma unroll
                for (int cb = 0; cb < 4; ++cb)
                    Tr[lr8][colw + cb * 32 + l31] = accL[cb][r] * scale;
            }
            lgkm_barrier();
            float* orow = outB + (size_t)(row_base + 8 * c + row8) * SEQ + half * 1024;
            #pragma unroll
            for (int j = 0; j < 4; ++j) {
                const f32x4 v = *reinterpret_cast<const f32x4*>(
                    &Tr[row8][half * 1024 + j * 256 + lane * 4]);
                *reinterpret_cast<f32x4*>(&orow[j * 256 + lane * 4]) = v;  // plain store
            }
            lgkm_barrier();
        }
        #pragma unroll 1
        for (int c = 0; c < 4; ++c) {          // chunks 4..7: accH
            #pragma unroll
            for (int rr = 0; rr < 4; ++rr) {
                const int r    = 4 * c + rr;
                const int lrow = 32 + rr + 8 * c + 4 * hi;
                const int lr8  = rr + 4 * hi;
                const float scale = inv_s[lrow];
                #pragma unroll
                for (int cb = 0; cb < 4; ++cb)
                    Tr[lr8][colw + cb * 32 + l31] = accH[cb][r] * scale;
            }
            lgkm_barrier();
            float* orow = outB + (size_t)(row_base + 32 + 8 * c + row8) * SEQ + half * 1024;
            #pragma unroll
            for (int j = 0; j < 4; ++j) {
                const f32x4 v = *reinterpret_cast<const f32x4*>(
                    &Tr[row8][half * 1024 + j * 256 + lane * 4]);
                *reinterpret_cast<f32x4*>(&orow[j * 256 + lane * 4]) = v;  // plain store
            }
            lgkm_barrier();
        }
    }
}

extern "C" void kernel_launch(void* const* d_in, const int* in_sizes, int n_in,
                              void* d_out, int out_size, void* d_ws, size_t ws_size,
                              hipStream_t stream) {
    (void)in_sizes; (void)n_in; (void)out_size; (void)ws_size;
    const float* x = (const float*)d_in[0];
    float* out = (float*)d_out;

    ushort* xb = (ushort*)d_ws;                                       // 16 MB bf16, k-major panels
    float*  sq = (float*)((char*)d_ws + (size_t)NB * SEQ * EDIM * 2); // 128 KB row norms

    prep_kernel<<<NB * SEQ / 4, 256, 0, stream>>>(x, xb, sq);

    dim3 grid(NB, 16);   // x = batch: flat%8 == batch%8 -> XCD locality; 256 WGs = 1/CU
    sims_main<<<grid, 1024, 0, stream>>>(xb, sq, out);
}

// Round 21
// 112.924 us; speedup vs baseline: 9.0799x; 9.0799x over previous
//
#include <hip/hip_runtime.h>
#include <hip/hip_bf16.h>

#define NB 16
#define SEQ 2048
#define EDIM 256

typedef __attribute__((ext_vector_type(16))) float f32x16;
typedef __attribute__((ext_vector_type(4)))  float f32x4;
typedef __attribute__((ext_vector_type(8)))  short short8;

static __device__ __forceinline__ ushort f2bf(float f) {
    uint32_t u = __float_as_uint(f);
    uint32_t r = (u + 0x7fffu + ((u >> 16) & 1u)) >> 16;
    return (ushort)r;
}
static __device__ __forceinline__ float bf2f(ushort h) {
    return __uint_as_float(((uint32_t)h) << 16);
}
// async global->LDS, 16 bytes per lane; LDS dest wave-uniform, global src per-lane.
static __device__ __forceinline__ void gll16(const ushort* g, ushort* l) {
    __builtin_amdgcn_global_load_lds(
        (const __attribute__((address_space(1))) uint32_t*)g,
        (__attribute__((address_space(3))) uint32_t*)l,
        16, 0, 0);
}
// raw barrier: lgkm-only wait, never drains in-flight vmem stores
static __device__ __forceinline__ void lgkm_barrier() {
    asm volatile("s_waitcnt lgkmcnt(0)" ::: "memory");
    __builtin_amdgcn_sched_barrier(0);
    __builtin_amdgcn_s_barrier();
    asm volatile("" ::: "memory");
}

// Kernel 1: fp32 -> bf16 in K-MAJOR PANEL layout xb[b][ks][t][j] (ks=e>>4,
// j=e&15), plus per-row sum of squares of the bf16-rounded values (distance
// diagonal cancels exactly against the fp32-accumulated MFMA gram).
__global__ void prep_kernel(const float* __restrict__ x,
                            ushort* __restrict__ xb,
                            float* __restrict__ sq) {
    __shared__ ushort sh[4][256];
    const int tid  = threadIdx.x;
    const int r    = tid >> 6;
    const int lane = tid & 63;
    const int grow = blockIdx.x * 4;
    const int row  = grow + r;

    const f32x4* xp = reinterpret_cast<const f32x4*>(x + (size_t)row * EDIM + lane * 4);
    const f32x4 v = __builtin_nontemporal_load(xp);
    ushort h0 = f2bf(v.x), h1 = f2bf(v.y), h2 = f2bf(v.z), h3 = f2bf(v.w);
    ushort4 h; h.x = h0; h.y = h1; h.z = h2; h.w = h3;
    *reinterpret_cast<ushort4*>(&sh[r][lane * 4]) = h;

    const float fx = bf2f(h0), fy = bf2f(h1), fz = bf2f(h2), fw = bf2f(h3);
    float s = fx * fx + fy * fy + fz * fz + fw * fw;
    #pragma unroll
    for (int m = 1; m < 64; m <<= 1) s += __shfl_xor(s, m);
    if (lane == 0) sq[row] = s;

    __syncthreads();

    const int b   = grow >> 11;
    const int t0  = grow & 2047;
    const int ksx = tid >> 4;
    const int idx = tid & 15;
    const int r2  = idx >> 2;
    const int j   = (idx & 3) * 4;
    ushort4 o = *reinterpret_cast<ushort4*>(&sh[r2][ksx * 16 + j]);
    *reinterpret_cast<ushort4*>(xb + (size_t)b * SEQ * EDIM
                                   + (size_t)ksx * SEQ * 16
                                   + (size_t)(t0 + r2) * 16 + j) = o;
}

// Kernel 2: fused gram-GEMM + one-pass softmax, 4 row-blocks per WG
// (R12 structure, empirically best: 112.9 us; reproduced 114.6). Session
// laws (all falsified alternatives in parentheses):
// (1) NEVER interleave output stores (or loads glued to them) with the
//     K-loop's panel loads -- concurrent load+store streams thrash the
//     4 MB XCD L2: FETCH/WRITE inflate 268+ MB, 2-3x slowdown
//     (R8 store-in-loop, R13 drain-slots, R16 preload-before-burst).
// (2) PLAIN stores beat nontemporal (R12 vs R11: +8 us; nt bypasses L2
//     absorption and backpressures at HBM rate).
// (3) Counted vmcnt(16) at block top keeps the 16 burst stores in flight
//     under the next K-loop without a drain.
// (4) The GEMM phase is not BW-bound: i8 halved traffic and regressed
//     (R14); 64-row reuse doubled intensity and spilled (R19); 16-row
//     2WG/CU co-residency regressed (R18). The schedule is
//     L2-phase-serialization-bound; this structure is its best point.
__global__ __launch_bounds__(1024, 4) void sims_main(
        const ushort* __restrict__ xb,
        const float*  __restrict__ sq,
        float* __restrict__ out) {
    __shared__ __align__(16) ushort Ab[2][16 * 512];  // 32 KB dbuf A panels
    __shared__ __align__(16) float Tr[8][2048];       // 64 KB transpose buffer
    __shared__ float red[32][17];
    __shared__ float inv_s[32];

    const int b    = blockIdx.x;        // batch -> XCD = flat%8 = b%8
    const int g    = blockIdx.y;        // rows [g*128,(g+1)*128)
    const int tid  = threadIdx.x;
    const int wave = tid >> 6;          // 0..15
    const int lane = tid & 63;
    const int l31  = lane & 31;
    const int hi   = lane >> 5;

    const ushort* xbB = xb + (size_t)b * SEQ * EDIM;
    const float*  sqB = sq + b * SEQ;
    float* outB = out + (size_t)b * SEQ * SEQ;

    const int colw = wave * 128;
    const ushort* bbase = xbB + ((size_t)colw + l31) * 16 + hi * 8;
    const int gl  = lane ^ ((lane >> 3) & 7);       // A-stage src chunk swizzle
    const int r6  = l31 * 2 + hi;
    const int pr6 = r6 ^ ((r6 >> 3) & 7);           // swizzled A read chunk

    constexpr float kC   = (float)(-1.4426950408889634 / 13.544);  // -log2(e)/T
    constexpr float m2kC = -2.0f * kC;
    float kcc[4];
    #pragma unroll
    for (int cb = 0; cb < 4; ++cb) kcc[cb] = kC * sqB[colw + cb * 32 + l31];

    // prologue: stage A panel for row-block 0
    gll16(xbB + (size_t)wave * (SEQ * 16) + ((g * 4 + 0) * 32 + (gl >> 1)) * 16 + (gl & 1) * 8,
          &Ab[0][wave * 512]);

    const int lr8r = wave >> 1;          // row within 8-row chunk this wave stores
    const int half = wave & 1;           // which 4KB half of the row

    #pragma unroll 1
    for (int rb = 0; rb < 4; ++rb) {
        // A-panel ready; prev row-block's <=16 stores may stay in flight.
        if (rb == 0) { asm volatile("s_waitcnt vmcnt(0)" ::: "memory"); }
        else         { asm volatile("s_waitcnt vmcnt(16)" ::: "memory"); }
        __builtin_amdgcn_sched_barrier(0);
        __builtin_amdgcn_s_barrier();
        __builtin_amdgcn_sched_barrier(0);

        const int row_base = (g * 4 + rb) * 32;
        const ushort* AbC = &Ab[rb & 1][0];

        f32x16 acc[4];
        #pragma unroll
        for (int cb = 0; cb < 4; ++cb) acc[cb] = (f32x16)0.0f;

        #pragma unroll 2
        for (int ks = 0; ks < 16; ++ks) {
            const ushort* bks = bbase + (size_t)ks * (SEQ * 16);
            short8 bv[4];
            #pragma unroll
            for (int cb = 0; cb < 4; ++cb)
                bv[cb] = *reinterpret_cast<const short8*>(bks + cb * 512);
            const short8 a = *reinterpret_cast<const short8*>(AbC + ks * 512 + pr6 * 8);
            #pragma unroll
            for (int cb = 0; cb < 4; ++cb)
                acc[cb] = __builtin_amdgcn_mfma_f32_32x32x16_bf16(a, bv[cb], acc[cb], 0, 0, 0);
        }

        // prefetch next row-block's A panel into the other buffer
        if (rb < 3) {
            gll16(xbB + (size_t)wave * (SEQ * 16)
                      + ((g * 4 + rb + 1) * 32 + (gl >> 1)) * 16 + (gl & 1) * 8,
                  &Ab[(rb + 1) & 1][wave * 512]);
        }

        // ---- epilogue: exp(-dist/T), full-row sums ----
        float part[16];
        #pragma unroll
        for (int r = 0; r < 16; ++r) {
            const float kcr = kC * sqB[row_base + (r & 3) + 8 * (r >> 2) + 4 * hi];
            float p = 0.0f;
            #pragma unroll
            for (int cb = 0; cb < 4; ++cb) {
                const float e = exp2f(fmaf(m2kC, acc[cb][r], kcr + kcc[cb]));
                acc[cb][r] = e;
                p += e;
            }
            part[r] = p;
        }
        #pragma unroll
        for (int r = 0; r < 16; ++r) {
            float p = part[r];
            p += __shfl_xor(p, 1);
            p += __shfl_xor(p, 2);
            p += __shfl_xor(p, 4);
            p += __shfl_xor(p, 8);
            p += __shfl_xor(p, 16);
            part[r] = p;
        }
        if (l31 == 0) {                  // lanes 0 and 32 of each wave
            #pragma unroll
            for (int r = 0; r < 16; ++r) {
                const int lrow = (r & 3) + 8 * (r >> 2) + 4 * hi;
                red[lrow][wave] = part[r];
            }
        }
        lgkm_barrier();
        if (tid < 32) {
            float s = 0.0f;
            #pragma unroll
            for (int w = 0; w < 16; ++w) s += red[tid][w];
            inv_s[tid] = 1.0f / s;
        }
        lgkm_barrier();

        // ---- transpose-burst store: 4 chunks x 8 rows through LDS ----
        #pragma unroll 1
        for (int c = 0; c < 4; ++c) {
            #pragma unroll
            for (int rr = 0; rr < 4; ++rr) {
                const int r    = 4 * c + rr;
                const int lrow = rr + 8 * c + 4 * hi;
                const int lr8  = rr + 4 * hi;
                const float scale = inv_s[lrow];
                #pragma unroll
                for (int cb = 0; cb < 4; ++cb)
                    Tr[lr8][colw + cb * 32 + l31] = acc[cb][r] * scale;
            }
            lgkm_barrier();
            float* orow = outB + (size_t)(row_base + 8 * c + lr8r) * SEQ + half * 1024;
            #pragma unroll
            for (int j = 0; j < 4; ++j) {
                const f32x4 v = *reinterpret_cast<const f32x4*>(
                    &Tr[lr8r][half * 1024 + j * 256 + lane * 4]);
                *reinterpret_cast<f32x4*>(&orow[j * 256 + lane * 4]) = v;   // plain store
            }
            lgkm_barrier();              // Tr reads complete; stores keep flying
        }
    }
}

extern "C" void kernel_launch(void* const* d_in, const int* in_sizes, int n_in,
                              void* d_out, int out_size, void* d_ws, size_t ws_size,
                              hipStream_t stream) {
    (void)in_sizes; (void)n_in; (void)out_size; (void)ws_size;
    const float* x = (const float*)d_in[0];
    float* out = (float*)d_out;

    ushort* xb = (ushort*)d_ws;                                       // 16 MB bf16, k-major panels
    float*  sq = (float*)((char*)d_ws + (size_t)NB * SEQ * EDIM * 2); // 128 KB row norms

    prep_kernel<<<NB * SEQ / 4, 256, 0, stream>>>(x, xb, sq);

    dim3 grid(NB, 16);   // x = batch: flat%8 == batch%8 -> XCD locality; 256 WGs = 1/CU
    sims_main<<<grid, 1024, 0, stream>>>(xb, sq, out);
}